// Round 5
// baseline (7160.695 us; speedup 1.0000x reference)
//
#include <hip/hip_runtime.h>
#include <math.h>

#define K_DIM 512
#define N_DIM 512
#define NLEAF 2048   // numpy pairwise leaves of 128 over 2^18 elements
#define BM 128
#define BN 128
#define BK 32

// ws float layout: [0]=mu, [1]=gamma, [16..2063]=leaf sums, [2064..4111]=leaf abs-sums,
//                  [4112..4112+262143]=precomputed effective weights (fast path only)
#define WS_LEAFS 16
#define WS_LEAFA (16 + NLEAF)
#define WS_EFF 4112

// ---------------------------------------------------------------------------
// NUMERICS CONTRACT (validated, absmax==0.0 — DO NOT CHANGE):
//  mu/gamma: numpy fp32 pairwise tree — 2048 leaves of 128 elems, each leaf
//    via 8-accumulator pattern + combine ((r0+r1)+(r2+r3))+((r4+r5)+(r6+r7)),
//    then perfect binary tree (left+right), scale by 2^-18.
//  eff_w = fl(fl(w + fl(sign(fl(w-mu)) - w)) * gamma)   (same DAG whether
//    fused in-gemm or precomputed in binarize_kernel — validated r3)
//  y: per-output single fp32 accumulator, fmaf chain, k STRICTLY ascending.
//  epilogue: yb=y+bias; cl=clip; rr=rintf(cl*7); q=rr/7; out=yb+(q-yb).
// ---------------------------------------------------------------------------

// Leaf sums: 8 threads per leaf (validated r4). Chain j: sequential adds over
// i, then __shfl_xor butterfly own+other reproduces the exact combine on lane0.
__global__ void leaf_kernel(const float* __restrict__ w, float* __restrict__ ws) {
  const int g = blockIdx.x * 256 + threadIdx.x;  // 0..16383
  const int leaf = g >> 3;
  const int j = g & 7;
  const float* p = w + leaf * 128 + j;
  float rs = p[0];
  float ra = fabsf(p[0]);
  #pragma unroll
  for (int i = 1; i < 16; ++i) {
    const float v = p[i * 8];
    rs += v;
    ra += fabsf(v);
  }
  {
    const float os = __shfl_xor(rs, 1); const float oa = __shfl_xor(ra, 1);
    rs = rs + os; ra = ra + oa;
  }
  {
    const float os = __shfl_xor(rs, 2); const float oa = __shfl_xor(ra, 2);
    rs = rs + os; ra = ra + oa;
  }
  {
    const float os = __shfl_xor(rs, 4); const float oa = __shfl_xor(ra, 4);
    rs = rs + os; ra = ra + oa;
  }
  if (j == 0) {
    ws[WS_LEAFS + leaf] = rs;
    ws[WS_LEAFA + leaf] = ra;
  }
}

// Binary-tree combine of the 2048 leaf partials, exact numpy pairing.
__global__ void tree_kernel(float* __restrict__ ws) {
  __shared__ float bufS[4096];
  __shared__ float bufA[4096];
  const int t = threadIdx.x;  // 256 threads, 1 block
  for (int i = t; i < NLEAF; i += 256) {
    bufS[i] = ws[WS_LEAFS + i];
    bufA[i] = ws[WS_LEAFA + i];
  }
  __syncthreads();
  int src = 0, n = NLEAF;
  while (n > 1) {
    const int dst = src + n;
    n >>= 1;
    for (int i = t; i < n; i += 256) {
      bufS[dst + i] = bufS[src + 2 * i] + bufS[src + 2 * i + 1];
      bufA[dst + i] = bufA[src + 2 * i] + bufA[src + 2 * i + 1];
    }
    __syncthreads();
    src = dst;
  }
  if (t == 0) {
    ws[0] = bufS[src] * (1.0f / 262144.0f);  // exact pow2 scale == np divide
    ws[1] = bufA[src] * (1.0f / 262144.0f);
  }
}

// Precompute eff_w once (0.26M elems) — exact same per-element fp32 DAG as the
// fused path (validated r3, absmax 0.0).
__global__ void binarize_kernel(const float* __restrict__ w, float* __restrict__ ws) {
  const float mu = ws[0];
  const float gamma = ws[1];
  const int i = (blockIdx.x * 256 + threadIdx.x) * 4;
  const float4 v = *(const float4*)&w[i];
  float4 e;
  const float* vi = &v.x;
  float* ei = &e.x;
  #pragma unroll
  for (int c = 0; c < 4; ++c) {
    const float wv = vi[c];
    const float wc = wv - mu;
    const float bin = (wc > 0.0f) ? 1.0f : ((wc < 0.0f) ? -1.0f : 0.0f);
    const float ste = wv + (bin - wv);
    ei[c] = ste * gamma;
  }
  *(float4*)&ws[WS_EFF + i] = e;
}

// FAST PATH: verbatim r0 tile/layout/compute (As[128][36] padded, Bs[32][132],
// 8x8 micro-tile, BK=32, both barriers) + T14 async-STAGE split: the 8 staging
// float4 loads for chunk c+1 issue BEFORE compute(c) (~4096 FMA-issue cycles
// of latency cover); reg->LDS writes land between the two barriers. B staging
// is a plain copy (STE hoisted to binarize_kernel). launch_bounds(256,3):
// reg cap 170 -> 3 waves/SIMD, 3 blocks/CU — same occupancy as r0.
__global__ __launch_bounds__(256, 3) void gemm_kernel_pre(
    const float* __restrict__ x, const float* __restrict__ eff,
    const float* __restrict__ bias, float* __restrict__ out) {
  __shared__ float As[BM][BK + 4];  // [m][k], stride 36 dwords (proven banking)
  __shared__ float Bs[BK][BN + 4];  // [k][n], stride 132 dwords (proven banking)

  const int t = threadIdx.x;
  const int tx = t & 15;   // col group: cols {tx*4..+3} and {64+tx*4..+3}
  const int ty = t >> 4;   // row group: rows {ty*4..+3} and {64+ty*4..+3}
  const int rowBase = blockIdx.x * BM;
  const int colBase = blockIdx.y * BN;

  // staging coords (verbatim r0)
  const int arow = t >> 3;          // + 32p, rows of A
  const int ak4 = (t & 7) * 4;      // k within chunk
  const int bk = t >> 5;            // + 8p, k rows of B
  const int bn4 = (t & 31) * 4;     // col within tile

  const float* aSrc = x + (size_t)(rowBase + arow) * K_DIM + ak4;      // +32p*K_DIM per p
  const float* bSrc = eff + (size_t)bk * N_DIM + colBase + bn4;        // +8p*N_DIM per p

  float acc[2][2][4][4];
  #pragma unroll
  for (int h = 0; h < 2; ++h)
    #pragma unroll
    for (int g = 0; g < 2; ++g)
      #pragma unroll
      for (int i = 0; i < 4; ++i)
        #pragma unroll
        for (int j = 0; j < 4; ++j) acc[h][g][i][j] = 0.0f;

  float4 pa[4], pb[4];

  // ---- prologue: stage chunk 0 ----
  #pragma unroll
  for (int p = 0; p < 4; ++p) pa[p] = *(const float4*)(aSrc + (size_t)(32 * p) * K_DIM);
  #pragma unroll
  for (int p = 0; p < 4; ++p) pb[p] = *(const float4*)(bSrc + (size_t)(8 * p) * N_DIM);
  #pragma unroll
  for (int p = 0; p < 4; ++p) *(float4*)&As[arow + 32 * p][ak4] = pa[p];
  #pragma unroll
  for (int p = 0; p < 4; ++p) *(float4*)&Bs[bk + 8 * p][bn4] = pb[p];
  __syncthreads();

  for (int kc = 0; kc < K_DIM; kc += BK) {  // 16 chunks, ascending k
    const bool more = (kc + BK) < K_DIM;
    // issue next-chunk loads BEFORE compute — latency hidden under 2048 FMAs
    if (more) {
      #pragma unroll
      for (int p = 0; p < 4; ++p)
        pa[p] = *(const float4*)(aSrc + (size_t)(32 * p) * K_DIM + (kc + BK));
      #pragma unroll
      for (int p = 0; p < 4; ++p)
        pb[p] = *(const float4*)(bSrc + (size_t)(8 * p + kc + BK) * N_DIM);
    }

    // compute (verbatim r0: 8 groups of 4 k, k strictly ascending)
    #pragma unroll
    for (int kg = 0; kg < 8; ++kg) {
      float4 a0[4], a1[4];
      #pragma unroll
      for (int i = 0; i < 4; ++i) {
        a0[i] = *(const float4*)&As[ty * 4 + i][kg * 4];
        a1[i] = *(const float4*)&As[64 + ty * 4 + i][kg * 4];
      }
      #pragma unroll
      for (int kk = 0; kk < 4; ++kk) {
        const float4 b0 = *(const float4*)&Bs[kg * 4 + kk][tx * 4];
        const float4 b1 = *(const float4*)&Bs[kg * 4 + kk][64 + tx * 4];
        const float* b0p = &b0.x;
        const float* b1p = &b1.x;
        #pragma unroll
        for (int i = 0; i < 4; ++i) {
          const float av0 = (&a0[i].x)[kk];
          const float av1 = (&a1[i].x)[kk];
          #pragma unroll
          for (int j = 0; j < 4; ++j) {
            acc[0][0][i][j] = fmaf(av0, b0p[j], acc[0][0][i][j]);
            acc[0][1][i][j] = fmaf(av0, b1p[j], acc[0][1][i][j]);
            acc[1][0][i][j] = fmaf(av1, b0p[j], acc[1][0][i][j]);
            acc[1][1][i][j] = fmaf(av1, b1p[j], acc[1][1][i][j]);
          }
        }
      }
    }
    __syncthreads();   // all waves done reading chunk kc

    if (more) {
      #pragma unroll
      for (int p = 0; p < 4; ++p) *(float4*)&As[arow + 32 * p][ak4] = pa[p];
      #pragma unroll
      for (int p = 0; p < 4; ++p) *(float4*)&Bs[bk + 8 * p][bn4] = pb[p];
    }
    __syncthreads();   // chunk kc+BK visible
  }

  // faithful fp32 epilogue (unchanged DAG)
  #pragma unroll
  for (int h = 0; h < 2; ++h)
    #pragma unroll
    for (int i = 0; i < 4; ++i) {
      const size_t row = (size_t)(rowBase + h * 64 + ty * 4 + i);
      #pragma unroll
      for (int g = 0; g < 2; ++g) {
        const int col = colBase + g * 64 + tx * 4;
        float4 o;
        float* op = &o.x;
        #pragma unroll
        for (int j = 0; j < 4; ++j) {
          const float yb = acc[h][g][i][j] + bias[col + j];
          const float cl = fminf(fmaxf(yb, -1.0f), 1.0f);
          const float t7 = cl * 7.0f;
          const float rr = rintf(t7);
          const float q = rr / 7.0f;
          op[j] = yb + (q - yb);
        }
        *(float4*)&out[row * N_DIM + col] = o;
      }
    }
}

// FALLBACK (ws too small): exact round-0 fused gemm, validated 434us.
__global__ __launch_bounds__(256, 4) void gemm_kernel_fused(
    const float* __restrict__ x, const float* __restrict__ w,
    const float* __restrict__ bias, const float* __restrict__ ws,
    float* __restrict__ out) {
  __shared__ float As[BM][BK + 4];
  __shared__ float Bs[BK][BN + 4];

  const float mu = ws[0];
  const float gamma = ws[1];
  const int t = threadIdx.x;
  const int tx = t & 15;
  const int ty = t >> 4;
  const int rowBase = blockIdx.x * BM;
  const int colBase = blockIdx.y * BN;

  float acc[2][2][4][4];
  #pragma unroll
  for (int h = 0; h < 2; ++h)
    #pragma unroll
    for (int g = 0; g < 2; ++g)
      #pragma unroll
      for (int i = 0; i < 4; ++i)
        #pragma unroll
        for (int j = 0; j < 4; ++j) acc[h][g][i][j] = 0.0f;

  for (int kc = 0; kc < K_DIM; kc += BK) {
    #pragma unroll
    for (int p = 0; p < 4; ++p) {
      const int r = (t >> 3) + 32 * p;
      const int k4 = (t & 7) * 4;
      const float4 v = *(const float4*)&x[(size_t)(rowBase + r) * K_DIM + kc + k4];
      *(float4*)&As[r][k4] = v;
    }
    #pragma unroll
    for (int p = 0; p < 4; ++p) {
      const int kk = (t >> 5) + 8 * p;
      const int n4 = (t & 31) * 4;
      const float4 v = *(const float4*)&w[(size_t)(kc + kk) * N_DIM + colBase + n4];
      float4 e;
      const float* vi = &v.x;
      float* ei = &e.x;
      #pragma unroll
      for (int c = 0; c < 4; ++c) {
        const float wv = vi[c];
        const float wc = wv - mu;
        const float bin = (wc > 0.0f) ? 1.0f : ((wc < 0.0f) ? -1.0f : 0.0f);
        const float ste = wv + (bin - wv);
        ei[c] = ste * gamma;
      }
      *(float4*)&Bs[kk][n4] = e;
    }
    __syncthreads();

    #pragma unroll
    for (int kg = 0; kg < 8; ++kg) {
      float4 a0[4], a1[4];
      #pragma unroll
      for (int i = 0; i < 4; ++i) {
        a0[i] = *(const float4*)&As[ty * 4 + i][kg * 4];
        a1[i] = *(const float4*)&As[64 + ty * 4 + i][kg * 4];
      }
      #pragma unroll
      for (int kk = 0; kk < 4; ++kk) {
        const float4 b0 = *(const float4*)&Bs[kg * 4 + kk][tx * 4];
        const float4 b1 = *(const float4*)&Bs[kg * 4 + kk][64 + tx * 4];
        const float* b0p = &b0.x;
        const float* b1p = &b1.x;
        #pragma unroll
        for (int i = 0; i < 4; ++i) {
          const float av0 = (&a0[i].x)[kk];
          const float av1 = (&a1[i].x)[kk];
          #pragma unroll
          for (int j = 0; j < 4; ++j) {
            acc[0][0][i][j] = fmaf(av0, b0p[j], acc[0][0][i][j]);
            acc[0][1][i][j] = fmaf(av0, b1p[j], acc[0][1][i][j]);
            acc[1][0][i][j] = fmaf(av1, b0p[j], acc[1][0][i][j]);
            acc[1][1][i][j] = fmaf(av1, b1p[j], acc[1][1][i][j]);
          }
        }
      }
    }
    __syncthreads();
  }

  #pragma unroll
  for (int h = 0; h < 2; ++h)
    #pragma unroll
    for (int i = 0; i < 4; ++i) {
      const size_t row = (size_t)(rowBase + h * 64 + ty * 4 + i);
      #pragma unroll
      for (int g = 0; g < 2; ++g) {
        const int col = colBase + g * 64 + tx * 4;
        float4 o;
        float* op = &o.x;
        #pragma unroll
        for (int j = 0; j < 4; ++j) {
          const float yb = acc[h][g][i][j] + bias[col + j];
          const float cl = fminf(fmaxf(yb, -1.0f), 1.0f);
          const float t7 = cl * 7.0f;
          const float rr = rintf(t7);
          const float q = rr / 7.0f;
          op[j] = yb + (q - yb);
        }
        *(float4*)&out[row * N_DIM + col] = o;
      }
    }
}

extern "C" void kernel_launch(void* const* d_in, const int* in_sizes, int n_in,
                              void* d_out, int out_size, void* d_ws, size_t ws_size,
                              hipStream_t stream) {
  const float* x = (const float*)d_in[0];
  const float* w = (const float*)d_in[1];
  const float* bias = (const float*)d_in[2];
  float* out = (float*)d_out;
  float* ws = (float*)d_ws;

  const int M = in_sizes[0] / K_DIM;  // 65536 rows

  leaf_kernel<<<(NLEAF * 8) / 256, 256, 0, stream>>>(w, ws);
  tree_kernel<<<1, 256, 0, stream>>>(ws);

  const size_t need = (size_t)(WS_EFF + K_DIM * N_DIM) * sizeof(float);  // ~1.06 MB
  if (ws_size >= need) {
    binarize_kernel<<<(K_DIM * N_DIM) / (256 * 4), 256, 0, stream>>>(w, ws);
    gemm_kernel_pre<<<dim3(M / BM, N_DIM / BN), 256, 0, stream>>>(
        x, ws + WS_EFF, bias, out);
  } else {
    gemm_kernel_fused<<<dim3(M / BM, N_DIM / BN), 256, 0, stream>>>(
        x, w, bias, ws, out);
  }
}

// Round 6
// 564.348 us; speedup vs baseline: 12.6884x; 12.6884x over previous
//
#include <hip/hip_runtime.h>
#include <math.h>

#define K_DIM 512
#define N_DIM 512
#define NLEAF 2048   // numpy pairwise leaves of 128 over 2^18 elements
#define BM 128
#define BN 128
#define BK 32

// ws float layout: [0]=mu, [1]=gamma, [16..2063]=leaf sums, [2064..4111]=leaf abs-sums,
//                  [4112..4112+262143]=precomputed effective weights (fast path only)
#define WS_LEAFS 16
#define WS_LEAFA (16 + NLEAF)
#define WS_EFF 4112

// ---------------------------------------------------------------------------
// NUMERICS CONTRACT (validated, absmax==0.0 — DO NOT CHANGE):
//  mu/gamma: numpy fp32 pairwise tree — 2048 leaves of 128 elems, each leaf
//    via 8-accumulator pattern + combine ((r0+r1)+(r2+r3))+((r4+r5)+(r6+r7)),
//    then perfect binary tree (left+right), scale by 2^-18.
//  eff_w = fl(fl(w + fl(sign(fl(w-mu)) - w)) * gamma)   (same DAG whether
//    fused in-gemm or precomputed in binarize_kernel — validated r3)
//  y: per-output single fp32 accumulator, fmaf chain, k STRICTLY ascending.
//  epilogue: yb=y+bias; cl=clip; rr=rintf(cl*7); q=rr/7; out=yb+(q-yb).
//
// STRUCTURAL LEDGER (5 rounds of evidence — do not retry):
//  r1 8x16 tile: -TLP, null.  r2/r5 reg-prefetch across unrolled body:
//  allocator spills acc to scratch (26 GB traffic).  r3 DMA-B: FETCH +60%,
//  vmcnt(0) serialization.  r4 A-direct-from-global: x re-read 4.6x.
//  r0 structure (below) is the validated local optimum; this round only
//  REMOVES instructions from it (STE hoisted to binarize pre-pass).
// ---------------------------------------------------------------------------

// Leaf sums: 8 threads per leaf (validated r4). Chain j: sequential adds over
// i, then __shfl_xor butterfly own+other reproduces the exact combine on lane0.
__global__ void leaf_kernel(const float* __restrict__ w, float* __restrict__ ws) {
  const int g = blockIdx.x * 256 + threadIdx.x;  // 0..16383
  const int leaf = g >> 3;
  const int j = g & 7;
  const float* p = w + leaf * 128 + j;
  float rs = p[0];
  float ra = fabsf(p[0]);
  #pragma unroll
  for (int i = 1; i < 16; ++i) {
    const float v = p[i * 8];
    rs += v;
    ra += fabsf(v);
  }
  {
    const float os = __shfl_xor(rs, 1); const float oa = __shfl_xor(ra, 1);
    rs = rs + os; ra = ra + oa;
  }
  {
    const float os = __shfl_xor(rs, 2); const float oa = __shfl_xor(ra, 2);
    rs = rs + os; ra = ra + oa;
  }
  {
    const float os = __shfl_xor(rs, 4); const float oa = __shfl_xor(ra, 4);
    rs = rs + os; ra = ra + oa;
  }
  if (j == 0) {
    ws[WS_LEAFS + leaf] = rs;
    ws[WS_LEAFA + leaf] = ra;
  }
}

// Binary-tree combine of the 2048 leaf partials, exact numpy pairing.
__global__ void tree_kernel(float* __restrict__ ws) {
  __shared__ float bufS[4096];
  __shared__ float bufA[4096];
  const int t = threadIdx.x;  // 256 threads, 1 block
  for (int i = t; i < NLEAF; i += 256) {
    bufS[i] = ws[WS_LEAFS + i];
    bufA[i] = ws[WS_LEAFA + i];
  }
  __syncthreads();
  int src = 0, n = NLEAF;
  while (n > 1) {
    const int dst = src + n;
    n >>= 1;
    for (int i = t; i < n; i += 256) {
      bufS[dst + i] = bufS[src + 2 * i] + bufS[src + 2 * i + 1];
      bufA[dst + i] = bufA[src + 2 * i] + bufA[src + 2 * i + 1];
    }
    __syncthreads();
    src = dst;
  }
  if (t == 0) {
    ws[0] = bufS[src] * (1.0f / 262144.0f);  // exact pow2 scale == np divide
    ws[1] = bufA[src] * (1.0f / 262144.0f);
  }
}

// Precompute eff_w once (0.26M elems) — exact same per-element fp32 DAG as the
// fused path (validated r3, absmax 0.0).
__global__ void binarize_kernel(const float* __restrict__ w, float* __restrict__ ws) {
  const float mu = ws[0];
  const float gamma = ws[1];
  const int i = (blockIdx.x * 256 + threadIdx.x) * 4;
  const float4 v = *(const float4*)&w[i];
  float4 e;
  const float* vi = &v.x;
  float* ei = &e.x;
  #pragma unroll
  for (int c = 0; c < 4; ++c) {
    const float wv = vi[c];
    const float wc = wv - mu;
    const float bin = (wc > 0.0f) ? 1.0f : ((wc < 0.0f) ? -1.0f : 0.0f);
    const float ste = wv + (bin - wv);
    ei[c] = ste * gamma;
  }
  *(float4*)&ws[WS_EFF + i] = e;
}

// FAST PATH: verbatim r0 structure (As[128][36] padded, Bs[32][132], 8x8
// micro-tile, BK=32, staging inside the chunk, both barriers, no held
// prefetch). ONLY change vs r0: B staging is a plain float4 copy from
// precomputed eff (STE VALU removed from the loop; load->ds_write dependency
// shortened). Access pattern of eff == access pattern of w => same caching.
__global__ __launch_bounds__(256, 4) void gemm_kernel_pre(
    const float* __restrict__ x, const float* __restrict__ eff,
    const float* __restrict__ bias, float* __restrict__ out) {
  __shared__ float As[BM][BK + 4];  // [m][k], stride 36 dwords (proven banking)
  __shared__ float Bs[BK][BN + 4];  // [k][n], stride 132 dwords (proven banking)

  const int t = threadIdx.x;
  const int tx = t & 15;   // col group: cols {tx*4..+3} and {64+tx*4..+3}
  const int ty = t >> 4;   // row group: rows {ty*4..+3} and {64+ty*4..+3}
  const int rowBase = blockIdx.x * BM;
  const int colBase = blockIdx.y * BN;

  float acc[2][2][4][4];
  #pragma unroll
  for (int h = 0; h < 2; ++h)
    #pragma unroll
    for (int g = 0; g < 2; ++g)
      #pragma unroll
      for (int i = 0; i < 4; ++i)
        #pragma unroll
        for (int j = 0; j < 4; ++j) acc[h][g][i][j] = 0.0f;

  for (int kc = 0; kc < K_DIM; kc += BK) {  // 16 chunks, ascending k
    // stage A: 128 rows x 32 k, coalesced (8 lanes * 16B = 128B per row)
    #pragma unroll
    for (int p = 0; p < 4; ++p) {
      const int r = (t >> 3) + 32 * p;
      const int k4 = (t & 7) * 4;
      const float4 v = *(const float4*)&x[(size_t)(rowBase + r) * K_DIM + kc + k4];
      *(float4*)&As[r][k4] = v;
    }
    // stage B: 32 k x 128 n, PLAIN COPY of precomputed eff (no STE VALU)
    #pragma unroll
    for (int p = 0; p < 4; ++p) {
      const int kk = (t >> 5) + 8 * p;
      const int n4 = (t & 31) * 4;
      const float4 v = *(const float4*)&eff[(size_t)(kc + kk) * N_DIM + colBase + n4];
      *(float4*)&Bs[kk][n4] = v;
    }
    __syncthreads();

    #pragma unroll
    for (int kg = 0; kg < 8; ++kg) {  // 8 groups of 4 k
      float4 a0[4], a1[4];
      #pragma unroll
      for (int i = 0; i < 4; ++i) {
        a0[i] = *(const float4*)&As[ty * 4 + i][kg * 4];
        a1[i] = *(const float4*)&As[64 + ty * 4 + i][kg * 4];
      }
      #pragma unroll
      for (int kk = 0; kk < 4; ++kk) {  // k ascending within group
        const float4 b0 = *(const float4*)&Bs[kg * 4 + kk][tx * 4];
        const float4 b1 = *(const float4*)&Bs[kg * 4 + kk][64 + tx * 4];
        const float* b0p = &b0.x;
        const float* b1p = &b1.x;
        #pragma unroll
        for (int i = 0; i < 4; ++i) {
          const float av0 = (&a0[i].x)[kk];
          const float av1 = (&a1[i].x)[kk];
          #pragma unroll
          for (int j = 0; j < 4; ++j) {
            acc[0][0][i][j] = fmaf(av0, b0p[j], acc[0][0][i][j]);
            acc[0][1][i][j] = fmaf(av0, b1p[j], acc[0][1][i][j]);
            acc[1][0][i][j] = fmaf(av1, b0p[j], acc[1][0][i][j]);
            acc[1][1][i][j] = fmaf(av1, b1p[j], acc[1][1][i][j]);
          }
        }
      }
    }
    __syncthreads();
  }

  // faithful fp32 epilogue (unchanged DAG)
  #pragma unroll
  for (int h = 0; h < 2; ++h)
    #pragma unroll
    for (int i = 0; i < 4; ++i) {
      const size_t row = (size_t)(rowBase + h * 64 + ty * 4 + i);
      #pragma unroll
      for (int g = 0; g < 2; ++g) {
        const int col = colBase + g * 64 + tx * 4;
        float4 o;
        float* op = &o.x;
        #pragma unroll
        for (int j = 0; j < 4; ++j) {
          const float yb = acc[h][g][i][j] + bias[col + j];
          const float cl = fminf(fmaxf(yb, -1.0f), 1.0f);
          const float t7 = cl * 7.0f;
          const float rr = rintf(t7);
          const float q = rr / 7.0f;
          op[j] = yb + (q - yb);
        }
        *(float4*)&out[row * N_DIM + col] = o;
      }
    }
}

// FALLBACK (ws too small): exact round-0 fused gemm, validated 434us.
__global__ __launch_bounds__(256, 4) void gemm_kernel_fused(
    const float* __restrict__ x, const float* __restrict__ w,
    const float* __restrict__ bias, const float* __restrict__ ws,
    float* __restrict__ out) {
  __shared__ float As[BM][BK + 4];
  __shared__ float Bs[BK][BN + 4];

  const float mu = ws[0];
  const float gamma = ws[1];
  const int t = threadIdx.x;
  const int tx = t & 15;
  const int ty = t >> 4;
  const int rowBase = blockIdx.x * BM;
  const int colBase = blockIdx.y * BN;

  float acc[2][2][4][4];
  #pragma unroll
  for (int h = 0; h < 2; ++h)
    #pragma unroll
    for (int g = 0; g < 2; ++g)
      #pragma unroll
      for (int i = 0; i < 4; ++i)
        #pragma unroll
        for (int j = 0; j < 4; ++j) acc[h][g][i][j] = 0.0f;

  for (int kc = 0; kc < K_DIM; kc += BK) {
    #pragma unroll
    for (int p = 0; p < 4; ++p) {
      const int r = (t >> 3) + 32 * p;
      const int k4 = (t & 7) * 4;
      const float4 v = *(const float4*)&x[(size_t)(rowBase + r) * K_DIM + kc + k4];
      *(float4*)&As[r][k4] = v;
    }
    #pragma unroll
    for (int p = 0; p < 4; ++p) {
      const int kk = (t >> 5) + 8 * p;
      const int n4 = (t & 31) * 4;
      const float4 v = *(const float4*)&w[(size_t)(kc + kk) * N_DIM + colBase + n4];
      float4 e;
      const float* vi = &v.x;
      float* ei = &e.x;
      #pragma unroll
      for (int c = 0; c < 4; ++c) {
        const float wv = vi[c];
        const float wc = wv - mu;
        const float bin = (wc > 0.0f) ? 1.0f : ((wc < 0.0f) ? -1.0f : 0.0f);
        const float ste = wv + (bin - wv);
        ei[c] = ste * gamma;
      }
      *(float4*)&Bs[kk][n4] = e;
    }
    __syncthreads();

    #pragma unroll
    for (int kg = 0; kg < 8; ++kg) {
      float4 a0[4], a1[4];
      #pragma unroll
      for (int i = 0; i < 4; ++i) {
        a0[i] = *(const float4*)&As[ty * 4 + i][kg * 4];
        a1[i] = *(const float4*)&As[64 + ty * 4 + i][kg * 4];
      }
      #pragma unroll
      for (int kk = 0; kk < 4; ++kk) {
        const float4 b0 = *(const float4*)&Bs[kg * 4 + kk][tx * 4];
        const float4 b1 = *(const float4*)&Bs[kg * 4 + kk][64 + tx * 4];
        const float* b0p = &b0.x;
        const float* b1p = &b1.x;
        #pragma unroll
        for (int i = 0; i < 4; ++i) {
          const float av0 = (&a0[i].x)[kk];
          const float av1 = (&a1[i].x)[kk];
          #pragma unroll
          for (int j = 0; j < 4; ++j) {
            acc[0][0][i][j] = fmaf(av0, b0p[j], acc[0][0][i][j]);
            acc[0][1][i][j] = fmaf(av0, b1p[j], acc[0][1][i][j]);
            acc[1][0][i][j] = fmaf(av1, b0p[j], acc[1][0][i][j]);
            acc[1][1][i][j] = fmaf(av1, b1p[j], acc[1][1][i][j]);
          }
        }
      }
    }
    __syncthreads();
  }

  #pragma unroll
  for (int h = 0; h < 2; ++h)
    #pragma unroll
    for (int i = 0; i < 4; ++i) {
      const size_t row = (size_t)(rowBase + h * 64 + ty * 4 + i);
      #pragma unroll
      for (int g = 0; g < 2; ++g) {
        const int col = colBase + g * 64 + tx * 4;
        float4 o;
        float* op = &o.x;
        #pragma unroll
        for (int j = 0; j < 4; ++j) {
          const float yb = acc[h][g][i][j] + bias[col + j];
          const float cl = fminf(fmaxf(yb, -1.0f), 1.0f);
          const float t7 = cl * 7.0f;
          const float rr = rintf(t7);
          const float q = rr / 7.0f;
          op[j] = yb + (q - yb);
        }
        *(float4*)&out[row * N_DIM + col] = o;
      }
    }
}

extern "C" void kernel_launch(void* const* d_in, const int* in_sizes, int n_in,
                              void* d_out, int out_size, void* d_ws, size_t ws_size,
                              hipStream_t stream) {
  const float* x = (const float*)d_in[0];
  const float* w = (const float*)d_in[1];
  const float* bias = (const float*)d_in[2];
  float* out = (float*)d_out;
  float* ws = (float*)d_ws;

  const int M = in_sizes[0] / K_DIM;  // 65536 rows

  leaf_kernel<<<(NLEAF * 8) / 256, 256, 0, stream>>>(w, ws);
  tree_kernel<<<1, 256, 0, stream>>>(ws);

  const size_t need = (size_t)(WS_EFF + K_DIM * N_DIM) * sizeof(float);  // ~1.06 MB
  if (ws_size >= need) {
    binarize_kernel<<<(K_DIM * N_DIM) / (256 * 4), 256, 0, stream>>>(w, ws);
    gemm_kernel_pre<<<dim3(M / BM, N_DIM / BN), 256, 0, stream>>>(
        x, ws + WS_EFF, bias, out);
  } else {
    gemm_kernel_fused<<<dim3(M / BM, N_DIM / BN), 256, 0, stream>>>(
        x, w, bias, ws, out);
  }
}